// Round 11
// baseline (603.192 us; speedup 1.0000x reference)
//
#include <hip/hip_runtime.h>
#include <math.h>

// ---------------------------------------------------------------------------
// NormDist (Lp, p=8) IBP AlexNet. Round 11:
//  - conv3x3: b128 row loads + 3-row register window -> LDS insts/cp 243->45
//    (LDS pipe was the conv3x3 bottleneck: 4 SIMDs share 1 LDS pipe).
//  - comb2+pool2 fused into conv3 staging (each elem staged by exactly 1 block).
//  - conv2 CC=8 (12 chunks): less partial traffic.
//  - fc: 4 batches per wave -> weight rows read 4x not 16x.
//  9 launches. lp8(d)=(sum d^8)^(1/8); relu after conv = no-op.
// ---------------------------------------------------------------------------

typedef float vf2 __attribute__((ext_vector_type(2)));

__device__ __forceinline__ float rt8(float s) { return sqrtf(sqrtf(sqrtf(s))); }

__device__ __forceinline__ void tap16(float w, float pc, float pl, float pu,
                                      float& aC, float& aL, float& aH)
{
    float a = pc - w; float a2 = a * a, a4 = a2 * a2; aC = fmaf(a4, a4, aC);
    float x = pl - w, y = pu - w;
    float dl = fmaxf(fmaxf(x, -y), 0.f);
    float e2 = dl * dl, e4 = e2 * e2; aL = fmaf(e4, e4, aL);
    float h2 = fmaxf(x * x, y * y);
    float h4 = h2 * h2; aH = fmaf(h4, h4, aH);
}

__device__ __forceinline__ void tap16v2(vf2 w, vf2 pc, vf2 pl, vf2 pu,
                                        vf2& aC, vf2& aL, vf2& aH)
{
    vf2 a = pc - w; vf2 a2 = a * a, a4 = a2 * a2;
    aC = __builtin_elementwise_fma(a4, a4, aC);
    vf2 x = pl - w, y = pu - w;
    vf2 zero = {0.f, 0.f};
    vf2 dl = __builtin_elementwise_max(__builtin_elementwise_max(x, -y), zero);
    vf2 e2 = dl * dl, e4 = e2 * e2;
    aL = __builtin_elementwise_fma(e4, e4, aL);
    vf2 h2 = __builtin_elementwise_max(x * x, y * y);
    vf2 h4 = h2 * h2;
    aH = __builtin_elementwise_fma(h4, h4, aH);
}

// prep: bid < 908 -> 64x64 LDS-tiled transpose of w2..w5 into c-pair layout
// T[((c/2)*KK+t)*(2*O) + o*2 + (c&1)]; else conv1 (round-split, 1536 blocks).
__launch_bounds__(256)
__global__ void prep_kernel(const float* __restrict__ W2, const float* __restrict__ W3,
                            const float* __restrict__ W4, const float* __restrict__ W5,
                            float* __restrict__ T2, float* __restrict__ T3,
                            float* __restrict__ T4, float* __restrict__ T5,
                            const float* __restrict__ IC, const float* __restrict__ IL,
                            const float* __restrict__ IU, const float* __restrict__ W1,
                            float* __restrict__ A)
{
    constexpr int nt2 = 152, nt3 = 216, nt4 = 324, nt5 = 216;
    constexpr int NTW = nt2 + nt3 + nt4 + nt5;  // 908
    __shared__ float u[3 * 3 * 1225];           // conv1 35x35 slab; >= 64*65
    int bid = blockIdx.x;
    int tid = threadIdx.x;

    if (bid < NTW) {
        const float* W; float* T; int O, CK, KK, t;
        if (bid < nt2)                  { W = W2; T = T2; O = 256; CK = 2400; KK = 25; t = bid; }
        else if (bid < nt2 + nt3)       { W = W3; T = T3; O = 384; CK = 2304; KK = 9; t = bid - nt2; }
        else if (bid < nt2 + nt3 + nt4) { W = W4; T = T4; O = 384; CK = 3456; KK = 9; t = bid - nt2 - nt3; }
        else                            { W = W5; T = T5; O = 256; CK = 3456; KK = 9; t = bid - nt2 - nt3 - nt4; }
        int tilesC = (CK + 63) / 64;
        int to = t / tilesC, tc = t - to * tilesC;
        int o0 = to * 64, c0 = tc * 64;
        int lane = tid & 63, wv = tid >> 6;
        #pragma unroll
        for (int i = 0; i < 16; ++i) {
            int row = wv + i * 4;
            int c = c0 + lane;
            u[row * 65 + lane] = (c < CK) ? W[(size_t)(o0 + row) * CK + c] : 0.f;
        }
        __syncthreads();
        #pragma unroll
        for (int i = 0; i < 16; ++i) {
            int row = wv + i * 4;
            int ck = c0 + row;
            if (ck < CK) {
                int c = ck / KK, tt = ck - c * KK;
                T[(size_t)((c >> 1) * KK + tt) * (2 * O) + (size_t)(o0 + lane) * 2 + (c & 1)]
                    = u[lane * 65 + row];
            }
        }
        return;
    }

    // conv1: [16,3,32,32] k7 s2 p2 -> raw d^8 sums [3][16,96,15,15]
    constexpr int PP = 1225, PW = 35, HW = 1024;
    int t = bid - NTW;
    int og = t % 24; t /= 24;
    int b  = t % 16; int r = t / 16;   // r in [0,4)

    for (int i = tid; i < 3 * 3 * PP; i += 256) u[i] = 0.f;
    __syncthreads();
    for (int tsel = 0; tsel < 3; ++tsel) {
        const float* src = (tsel == 0 ? IC : (tsel == 1 ? IL : IU)) + (size_t)b * 3 * HW;
        for (int e = tid; e < 3 * HW; e += 256) {
            int c = e / HW, p = e % HW;
            int pr = p / 32, pw_ = p % 32;
            u[c * 3 * PP + tsel * PP + (pr + 2) * PW + (pw_ + 2)] = src[e];
        }
    }
    __syncthreads();

    int wave = tid >> 6, lane = tid & 63;
    int o = og * 4 + wave;
    const float* wp = W1 + (size_t)o * 147;
    int pos = r * 64 + lane;
    if (pos < 225) {
        int oh = pos / 15, ow = pos % 15;
        const float* sl = u + (oh * 2) * PW + ow * 2;
        float aC = 0.f, aL = 0.f, aH = 0.f;
        #pragma unroll
        for (int c = 0; c < 3; ++c) {
            #pragma unroll
            for (int kh = 0; kh < 7; ++kh)
                #pragma unroll
                for (int kw = 0; kw < 7; ++kw) {
                    float w = wp[c * 49 + kh * 7 + kw];
                    tap16(w, sl[kh * PW + kw], sl[PP + kh * PW + kw],
                          sl[2 * PP + kh * PW + kw], aC, aL, aH);
                }
            sl += 3 * PP;
        }
        size_t N = (size_t)16 * 96 * 225;
        size_t oi = ((size_t)b * 96 + o) * 225 + pos;
        A[oi] = aC; A[N + oi] = aL; A[2 * N + oi] = aH;
    }
}

// conv2: block=(chunk,b,oh), thread=o. Staging fuses pool1(3x3 s2)+rt8 from
// conv1 raw sums A. slab: [cp][tsel(3)][r(5)][col(12)][par(2)]
template<int CC>
__launch_bounds__(256)
__global__ void conv2_kernel(const float* __restrict__ A, const float* __restrict__ WT,
                             float* __restrict__ P)
{
    constexpr int B = 16, Cin = 96, O = 256;
    constexpr int CP = CC / 2;
    constexpr size_t N = (size_t)B * O * 49;
    constexpr size_t NA = (size_t)B * 96 * 225;
    __shared__ __align__(16) float slab[CP * 360];
    int x = blockIdx.x;
    int oh   = x % 7;
    int b    = (x / 7) % B;
    int chunk = x / (7 * B);
    int c0 = chunk * CC;
    int tid = threadIdx.x;

    for (int i = tid; i < CP * 360; i += 256) {
        int cp = i / 360; int rem = i - cp * 360;
        int tsel = rem / 120; int rr = rem - tsel * 120;
        int r = rr / 24; int cpar = rr - r * 24;
        int col = cpar >> 1, par = cpar & 1;
        int c = c0 + cp * 2 + par;
        int ih = oh + r - 2, iw = col - 2;
        float v = 0.f;
        if (col < 11 && (unsigned)ih < 7u && (unsigned)iw < 7u) {
            const float* ap = A + (size_t)tsel * NA + ((size_t)b * 96 + c) * 225
                            + (ih * 2) * 15 + iw * 2;
            float m = 0.f;  // sums >= 0
            #pragma unroll
            for (int pi = 0; pi < 3; ++pi)
                #pragma unroll
                for (int pj = 0; pj < 3; ++pj)
                    m = fmaxf(m, ap[pi * 15 + pj]);
            v = rt8(m);
        }
        slab[i] = v;
    }
    __syncthreads();

    int o = tid;
    vf2 aC2[7], aL2[7], aH2[7];
    vf2 zero = {0.f, 0.f};
    #pragma unroll
    for (int u = 0; u < 7; ++u) { aC2[u] = zero; aL2[u] = zero; aH2[u] = zero; }

    for (int cp = 0; cp < CP; ++cp) {
        const float* wp = WT + (size_t)((c0 / 2 + cp) * 25) * (2 * O) + 2 * o;
        const float* sb = slab + cp * 360;
        #pragma unroll
        for (int r = 0; r < 5; ++r) {
            vf2 wr[5];
            #pragma unroll
            for (int kw = 0; kw < 5; ++kw)
                wr[kw] = *(const vf2*)(wp + (size_t)(r * 5 + kw) * (2 * O));
            vf2 X[12], L[12], U[12];
            #pragma unroll
            for (int i2 = 0; i2 < 12; ++i2) {
                X[i2] = *(const vf2*)(sb + r * 24 + i2 * 2);
                L[i2] = *(const vf2*)(sb + 120 + r * 24 + i2 * 2);
                U[i2] = *(const vf2*)(sb + 240 + r * 24 + i2 * 2);
            }
            #pragma unroll
            for (int ow = 0; ow < 7; ++ow)
                #pragma unroll
                for (int kw = 0; kw < 5; ++kw)
                    tap16v2(wr[kw], X[ow + kw], L[ow + kw], U[ow + kw],
                            aC2[ow], aL2[ow], aH2[ow]);
        }
    }

    float* Pc = P + (size_t)chunk * 3 * N;
    size_t rowbase = ((size_t)(b * 7 + oh) * 7) * O + o;
    #pragma unroll
    for (int u = 0; u < 7; ++u) {
        Pc[rowbase + (size_t)u * O]         = aC2[u].x + aC2[u].y;
        Pc[N + rowbase + (size_t)u * O]     = aL2[u].x + aL2[u].y;
        Pc[2 * N + rowbase + (size_t)u * O] = aH2[u].x + aH2[u].y;
    }
}

#define LDROW(R, off, iy) { \
    float4 q0 = *(const float4*)(sb + (off) + (iy) * 12); \
    float4 q1 = *(const float4*)(sb + (off) + (iy) * 12 + 4); \
    vf2   q2 = *(const vf2*)(sb + (off) + (iy) * 12 + 8); \
    R[iy][0] = vf2{q0.x, q0.y}; R[iy][1] = vf2{q0.z, q0.w}; \
    R[iy][2] = vf2{q1.x, q1.y}; R[iy][3] = vf2{q1.z, q1.w}; \
    R[iy][4] = q2; }

#define TAPS(py) \
    _Pragma("unroll") for (int px = 0; px < 3; ++px) \
    _Pragma("unroll") for (int ky = 0; ky < 3; ++ky) \
    _Pragma("unroll") for (int kx = 0; kx < 3; ++kx) \
        tap16v2(w2[ky * 3 + kx], X[(py) + ky][px + kx], L[(py) + ky][px + kx], \
                U[(py) + ky][px + kx], aC2[(py) * 3 + px], aL2[(py) * 3 + px], \
                aH2[(py) * 3 + px]);

// conv3/4/5: block=(chunk,b), thread=o, channel-pair packed, b128 row loads +
// 3-row register window. slab: [cp][tsel(3)][iy(5)][col(6)][par(2)] (row=12f).
// POOL: staging = rt8(max_{3x3 pool} sum_{12 conv2 chunks}).
// NCHIN>0: staging = rt8(sum of NCHIN partial chunks). NCHIN==0: direct.
template<int CC, int NCHIN, bool POOL>
__launch_bounds__(384)
__global__ void conv3x3_kernel(const float* __restrict__ IN, const float* __restrict__ WT,
                               float* __restrict__ P, int B, int Cin, int O)
{
    constexpr int CP = CC / 2;
    __shared__ __align__(16) float slab[CP * 180];
    int x = blockIdx.x;
    int b = x % B;
    int chunk = x / B;
    int c0 = chunk * CC;
    int tid = threadIdx.x;

    size_t NN = (size_t)B * Cin * 9;
    constexpr size_t N2 = (size_t)16 * 256 * 49;
    for (int i = tid; i < CP * 180; i += blockDim.x) {
        int cp = i / 180; int rem = i - cp * 180;
        int tsel = rem / 60; int rr = rem - tsel * 60;
        int iy = rr / 12; int cc2 = rr - iy * 12;
        int col = cc2 >> 1, par = cc2 & 1;
        int ih = iy - 1, iw = col - 1;
        int c = c0 + cp * 2 + par;
        float v = 0.f;
        if ((unsigned)ih < 3u && (unsigned)iw < 3u) {
            if (POOL) {
                float m = 0.f;
                #pragma unroll
                for (int pi = 0; pi < 3; ++pi)
                    #pragma unroll
                    for (int pj = 0; pj < 3; ++pj) {
                        int sp = (ih * 2 + pi) * 7 + (iw * 2 + pj);
                        size_t base = (size_t)tsel * N2 + ((size_t)b * 49 + sp) * 256 + c;
                        float s = 0.f;
                        #pragma unroll
                        for (int ch = 0; ch < 12; ++ch) s += IN[(size_t)ch * 3 * N2 + base];
                        m = fmaxf(m, s);
                    }
                v = rt8(m);
            } else if (NCHIN == 0) {
                v = IN[(size_t)tsel * NN + ((size_t)b * 9 + (ih * 3 + iw)) * Cin + c];
            } else {
                size_t base = (size_t)tsel * NN + ((size_t)b * 9 + (ih * 3 + iw)) * Cin + c;
                float s = 0.f;
                #pragma unroll 8
                for (int ch = 0; ch < NCHIN; ++ch) s += IN[(size_t)ch * 3 * NN + base];
                v = rt8(s);
            }
        }
        slab[i] = v;
    }
    __syncthreads();

    int o = tid;
    vf2 aC2[9], aL2[9], aH2[9];
    vf2 zero = {0.f, 0.f};
    #pragma unroll
    for (int u = 0; u < 9; ++u) { aC2[u] = zero; aL2[u] = zero; aH2[u] = zero; }

    for (int cp = 0; cp < CP; ++cp) {
        const float* wp = WT + (size_t)((c0 / 2 + cp) * 9) * (2 * O) + 2 * o;
        vf2 w2[9];
        #pragma unroll
        for (int t = 0; t < 9; ++t) w2[t] = *(const vf2*)(wp + (size_t)t * (2 * O));
        const float* sb = slab + cp * 180;
        vf2 X[5][5], L[5][5], U[5][5];
        LDROW(X, 0, 0) LDROW(L, 60, 0) LDROW(U, 120, 0)
        LDROW(X, 0, 1) LDROW(L, 60, 1) LDROW(U, 120, 1)
        LDROW(X, 0, 2) LDROW(L, 60, 2) LDROW(U, 120, 2)
        TAPS(0)
        LDROW(X, 0, 3) LDROW(L, 60, 3) LDROW(U, 120, 3)
        TAPS(1)
        LDROW(X, 0, 4) LDROW(L, 60, 4) LDROW(U, 120, 4)
        TAPS(2)
    }

    size_t N = (size_t)B * O * 9;
    float* Pc = P + (size_t)chunk * 3 * N;
    size_t base = ((size_t)b * 9) * O + o;
    #pragma unroll
    for (int u = 0; u < 9; ++u) {
        Pc[base + (size_t)u * O]         = aC2[u].x + aC2[u].y;
        Pc[N + base + (size_t)u * O]     = aL2[u].x + aL2[u].y;
        Pc[2 * N + base + (size_t)u * O] = aH2[u].x + aH2[u].y;
    }
}

// conv5 combine -> standard [tsel][b][O][9] layout for fc1.
__global__ void comb5_std(const float* __restrict__ P, float* __restrict__ G, int NCH)
{
    constexpr int B = 16, O = 256;
    constexpr size_t N = (size_t)B * O * 9;
    size_t idx = (size_t)blockIdx.x * blockDim.x + threadIdx.x;
    if (idx >= 3 * N) return;
    float s = 0.f;
    for (int ch = 0; ch < NCH; ++ch) s += P[(size_t)ch * 3 * N + idx];
    int o = (int)(idx % O); size_t t = idx / O;
    int pos = (int)(t % 9); t /= 9;
    int b = (int)(t % B); int tsel = (int)(t / B);
    G[(size_t)tsel * N + ((size_t)b * O + o) * 9 + pos] = rt8(s);
}

// fc1/fc2: wave per (o, b-group of 4); weight row read once per 4 batches.
__launch_bounds__(256)
__global__ void fc_gemv4(const float* __restrict__ IC, const float* __restrict__ IL,
                         const float* __restrict__ IU, const float* __restrict__ W,
                         float* __restrict__ OUT, int In, int Out)
{
    constexpr int B = 16;
    int gw = (int)((blockIdx.x * blockDim.x + threadIdx.x) >> 6);
    int lane = threadIdx.x & 63;
    if (gw >= Out * 4) return;
    int o = gw % Out, bg = gw / Out;
    int b0 = bg * 4;
    const float4* wr = (const float4*)(W + (size_t)o * In);
    const float4* cr[4]; const float4* lr[4]; const float4* ur[4];
    #pragma unroll
    for (int q = 0; q < 4; ++q) {
        cr[q] = (const float4*)(IC + (size_t)(b0 + q) * In);
        lr[q] = (const float4*)(IL + (size_t)(b0 + q) * In);
        ur[q] = (const float4*)(IU + (size_t)(b0 + q) * In);
    }
    int In4 = In >> 2;
    float sc[4] = {0.f, 0.f, 0.f, 0.f};
    float sm[4] = {0.f, 0.f, 0.f, 0.f};
    float sr[4] = {0.f, 0.f, 0.f, 0.f};
    for (int i = lane; i < In4; i += 64) {
        float4 w4 = wr[i];
        float ax = fabsf(w4.x), ay = fabsf(w4.y), az = fabsf(w4.z), aw = fabsf(w4.w);
        #pragma unroll
        for (int q = 0; q < 4; ++q) {
            float4 c4 = cr[q][i], l4 = lr[q][i], u4 = ur[q][i];
            sc[q] = fmaf(c4.x, w4.x, sc[q]); sc[q] = fmaf(c4.y, w4.y, sc[q]);
            sc[q] = fmaf(c4.z, w4.z, sc[q]); sc[q] = fmaf(c4.w, w4.w, sc[q]);
            sm[q] = fmaf((l4.x + u4.x) * 0.5f, w4.x, sm[q]);
            sm[q] = fmaf((l4.y + u4.y) * 0.5f, w4.y, sm[q]);
            sm[q] = fmaf((l4.z + u4.z) * 0.5f, w4.z, sm[q]);
            sm[q] = fmaf((l4.w + u4.w) * 0.5f, w4.w, sm[q]);
            sr[q] = fmaf((u4.x - l4.x) * 0.5f, ax, sr[q]);
            sr[q] = fmaf((u4.y - l4.y) * 0.5f, ay, sr[q]);
            sr[q] = fmaf((u4.z - l4.z) * 0.5f, az, sr[q]);
            sr[q] = fmaf((u4.w - l4.w) * 0.5f, aw, sr[q]);
        }
    }
    #pragma unroll
    for (int off = 32; off; off >>= 1) {
        #pragma unroll
        for (int q = 0; q < 4; ++q) {
            sc[q] += __shfl_xor(sc[q], off);
            sm[q] += __shfl_xor(sm[q], off);
            sr[q] += __shfl_xor(sr[q], off);
        }
    }
    if (lane == 0) {
        size_t N = (size_t)B * Out;
        #pragma unroll
        for (int q = 0; q < 4; ++q) {
            size_t idx = (size_t)(b0 + q) * Out + o;
            OUT[idx]         = fmaxf(sc[q], 0.f);
            OUT[N + idx]     = fmaxf(sm[q] - sr[q], 0.f);
            OUT[2 * N + idx] = fmaxf(sm[q] + sr[q], 0.f);
        }
    }
}

__global__ void bound_linear_kernel(
    const float* __restrict__ IC, const float* __restrict__ IL, const float* __restrict__ IU,
    const float* __restrict__ W, const float* __restrict__ bias,
    float* __restrict__ OC, float* __restrict__ OL, float* __restrict__ OU,
    int B, int In, int Out)
{
    int idx = blockIdx.x * blockDim.x + threadIdx.x;
    if (idx >= B * Out) return;
    int o = idx % Out, b = idx / Out;
    const float* wr = W  + (size_t)o * In;
    const float* cr = IC + (size_t)b * In;
    const float* lr = IL + (size_t)b * In;
    const float* ur = IU + (size_t)b * In;
    float sc = 0.f, sm = 0.f, sr = 0.f;
    for (int i = 0; i < In; ++i) {
        float w = wr[i];
        sc = fmaf(cr[i], w, sc);
        sm = fmaf((lr[i] + ur[i]) * 0.5f, w, sm);
        sr = fmaf((ur[i] - lr[i]) * 0.5f, fabsf(w), sr);
    }
    float bb = bias[o]; sc += bb; sm += bb;
    OC[idx] = -sc; OL[idx] = -(sm - sr); OU[idx] = -(sm + sr);
}

extern "C" void kernel_launch(void* const* d_in, const int* in_sizes, int n_in,
                              void* d_out, int out_size, void* d_ws, size_t ws_size,
                              hipStream_t stream)
{
    const float* x   = (const float*)d_in[0];
    const float* lo  = (const float*)d_in[1];
    const float* hi  = (const float*)d_in[2];
    const float* w1  = (const float*)d_in[3];
    const float* w2  = (const float*)d_in[4];
    const float* w3  = (const float*)d_in[5];
    const float* w4  = (const float*)d_in[6];
    const float* w5  = (const float*)d_in[7];
    const float* fw1 = (const float*)d_in[8];
    const float* fw2 = (const float*)d_in[9];
    const float* fw3 = (const float*)d_in[10];
    const float* fb3 = (const float*)d_in[11];
    float* out = (float*)d_out;
    float* ws  = (float*)d_ws;

    const size_t n_c1 = 16u * 96 * 225;       // conv1 raw
    const size_t n_c5 = 16u * 256 * 9;
    const size_t n_f1 = 16u * 1024;
    const size_t n_f2 = 16u * 512;
    const size_t N3   = 16u * 384 * 9;        // conv3/conv4 plane

    float* A   = ws;                 // conv1 raw sums: 3*n_c1
    float* G   = A  + 3 * n_c1;      // conv5 combined, standard: 3*n_c5
    float* H   = G  + 3 * n_c5;      // fc1 out
    float* I   = H  + 3 * n_f1;      // fc2 out
    float* WT2 = I  + 3 * n_f2;      // 614400
    float* WT3 = WT2 + 614400;       // 884736
    float* WT4 = WT3 + 884736;       // 1327104
    float* WT5 = WT4 + 1327104;      // 884736
    float* SP2 = WT5 + 884736;       // conv2 partials 12*3*200704 = 7.23M
    float* SPb = SP2;                // conv4 partials alias (SP2 dead): 48*3*N3 = 7.96M
    float* SPa = SP2 + 48u * 3 * N3; // conv3 partials: 32*3*N3 = 5.31M
    float* SPc = SPa;                // conv5 partials alias (SPa dead): 48*3*n_c5 = 5.31M

    const int BS = 256;
    auto grid = [](size_t tot) { return dim3((unsigned)((tot + 255) / 256)); };

    // prep: weight transposes (908) + conv1 (1536)
    prep_kernel<<<908 + 1536, BS, 0, stream>>>(
        w2, w3, w4, w5, WT2, WT3, WT4, WT5, x, lo, hi, w1, A);
    // conv2 (staging fuses pool1+rt8): NCH=12, CC=8; 1344 blocks
    conv2_kernel<8><<<12 * 16 * 7, 256, 0, stream>>>(A, WT2, SP2);
    // conv3: staging fuses comb2 (12-chunk sum) + pool2 + rt8; Cin=256 O=384
    conv3x3_kernel<8, 0, true><<<32 * 16, 384, 0, stream>>>(SP2, WT3, SPa, 16, 256, 384);
    // conv4: staging = rt8(sum of 32 conv3 partials); writes SPb (=SP2, now dead)
    conv3x3_kernel<8, 32, false><<<48 * 16, 384, 0, stream>>>(SPa, WT4, SPb, 16, 384, 384);
    // conv5: staging = rt8(sum of 48 conv4 partials); writes SPc (=SPa, now dead)
    conv3x3_kernel<8, 48, false><<<48 * 16, 256, 0, stream>>>(SPb, WT5, SPc, 16, 384, 256);
    // conv5 combine -> standard layout
    comb5_std<<<grid(3 * n_c5), BS, 0, stream>>>(SPc, G, 48);
    // fc1: 2304 -> 1024, relu; 4096 waves (4 b per wave)
    fc_gemv4<<<grid(4096u * 64), BS, 0, stream>>>(
        G, G + n_c5, G + 2 * n_c5, fw1, H, 2304, 1024);
    // fc2: 1024 -> 512, relu; 2048 waves
    fc_gemv4<<<grid(2048u * 64), BS, 0, stream>>>(
        H, H + n_f1, H + 2 * n_f1, fw2, I, 1024, 512);
    // fc3: 512 -> 10, +bias, negate+swap: out = [-c | -u | -l]
    bound_linear_kernel<<<grid(160), BS, 0, stream>>>(
        I, I + n_f2, I + 2 * n_f2, fw3, fb3,
        out, out + 320, out + 160, 16, 512, 10);
}

// Round 12
// 574.578 us; speedup vs baseline: 1.0498x; 1.0498x over previous
//
#include <hip/hip_runtime.h>
#include <math.h>

// ---------------------------------------------------------------------------
// NormDist (Lp, p=8) IBP AlexNet. Round 12 = Round 10 structure (known-good)
// + fc_gemv4 (weight rows read once per 4 batches).
// Round-11 lessons: conv2 CC=8 cut grid/occupancy (regression); conv3x3 full
// 5x5 register window cost >220 VGPR on 6-wave blocks -> occupancy cliff;
// fusing comb2+pool2 into conv3 staging de-coalesced it. All reverted.
//  - prep kernel = batched weight transpose + conv1 (bid-routed).
//  - pool1+rt8 fused into conv2 staging; comb2+pool2 separate coalesced kernel;
//    conv-combines fused into conv4/conv5 staging. 10 launches.
// HW model: fp32 VALU = 2 FLOP/lane/cy (pk-f32 saves issue slots/VGPR only).
// lp8(d) = (sum d^8)^(1/8); relu after conv = no-op (norms >= 0).
// ---------------------------------------------------------------------------

typedef float vf2 __attribute__((ext_vector_type(2)));

__device__ __forceinline__ float rt8(float s) { return sqrtf(sqrtf(sqrtf(s))); }

__device__ __forceinline__ void tap16(float w, float pc, float pl, float pu,
                                      float& aC, float& aL, float& aH)
{
    float a = pc - w; float a2 = a * a, a4 = a2 * a2; aC = fmaf(a4, a4, aC);
    float x = pl - w, y = pu - w;
    float dl = fmaxf(fmaxf(x, -y), 0.f);
    float e2 = dl * dl, e4 = e2 * e2; aL = fmaf(e4, e4, aL);
    float h2 = fmaxf(x * x, y * y);
    float h4 = h2 * h2; aH = fmaf(h4, h4, aH);
}

__device__ __forceinline__ void tap16v2(vf2 w, vf2 pc, vf2 pl, vf2 pu,
                                        vf2& aC, vf2& aL, vf2& aH)
{
    vf2 a = pc - w; vf2 a2 = a * a, a4 = a2 * a2;
    aC = __builtin_elementwise_fma(a4, a4, aC);
    vf2 x = pl - w, y = pu - w;
    vf2 zero = {0.f, 0.f};
    vf2 dl = __builtin_elementwise_max(__builtin_elementwise_max(x, -y), zero);
    vf2 e2 = dl * dl, e4 = e2 * e2;
    aL = __builtin_elementwise_fma(e4, e4, aL);
    vf2 h2 = __builtin_elementwise_max(x * x, y * y);
    vf2 h4 = h2 * h2;
    aH = __builtin_elementwise_fma(h4, h4, aH);
}

// prep: bid < 908 -> 64x64 LDS-tiled transpose of w2..w5 into c-pair layout
// T[((c/2)*KK+t)*(2*O) + o*2 + (c&1)]; else conv1 (round-split, 1536 blocks).
__launch_bounds__(256)
__global__ void prep_kernel(const float* __restrict__ W2, const float* __restrict__ W3,
                            const float* __restrict__ W4, const float* __restrict__ W5,
                            float* __restrict__ T2, float* __restrict__ T3,
                            float* __restrict__ T4, float* __restrict__ T5,
                            const float* __restrict__ IC, const float* __restrict__ IL,
                            const float* __restrict__ IU, const float* __restrict__ W1,
                            float* __restrict__ A)
{
    constexpr int nt2 = 152, nt3 = 216, nt4 = 324, nt5 = 216;
    constexpr int NTW = nt2 + nt3 + nt4 + nt5;  // 908
    __shared__ float u[3 * 3 * 1225];           // conv1 35x35 slab; >= 64*65
    int bid = blockIdx.x;
    int tid = threadIdx.x;

    if (bid < NTW) {
        const float* W; float* T; int O, CK, KK, t;
        if (bid < nt2)                  { W = W2; T = T2; O = 256; CK = 2400; KK = 25; t = bid; }
        else if (bid < nt2 + nt3)       { W = W3; T = T3; O = 384; CK = 2304; KK = 9; t = bid - nt2; }
        else if (bid < nt2 + nt3 + nt4) { W = W4; T = T4; O = 384; CK = 3456; KK = 9; t = bid - nt2 - nt3; }
        else                            { W = W5; T = T5; O = 256; CK = 3456; KK = 9; t = bid - nt2 - nt3 - nt4; }
        int tilesC = (CK + 63) / 64;
        int to = t / tilesC, tc = t - to * tilesC;
        int o0 = to * 64, c0 = tc * 64;
        int lane = tid & 63, wv = tid >> 6;
        #pragma unroll
        for (int i = 0; i < 16; ++i) {
            int row = wv + i * 4;
            int c = c0 + lane;
            u[row * 65 + lane] = (c < CK) ? W[(size_t)(o0 + row) * CK + c] : 0.f;
        }
        __syncthreads();
        #pragma unroll
        for (int i = 0; i < 16; ++i) {
            int row = wv + i * 4;
            int ck = c0 + row;
            if (ck < CK) {
                int c = ck / KK, tt = ck - c * KK;
                T[(size_t)((c >> 1) * KK + tt) * (2 * O) + (size_t)(o0 + lane) * 2 + (c & 1)]
                    = u[lane * 65 + row];
            }
        }
        return;
    }

    // conv1: [16,3,32,32] k7 s2 p2 -> raw d^8 sums [3][16,96,15,15]
    constexpr int PP = 1225, PW = 35, HW = 1024;
    int t = bid - NTW;
    int og = t % 24; t /= 24;
    int b  = t % 16; int r = t / 16;   // r in [0,4)

    for (int i = tid; i < 3 * 3 * PP; i += 256) u[i] = 0.f;
    __syncthreads();
    for (int tsel = 0; tsel < 3; ++tsel) {
        const float* src = (tsel == 0 ? IC : (tsel == 1 ? IL : IU)) + (size_t)b * 3 * HW;
        for (int e = tid; e < 3 * HW; e += 256) {
            int c = e / HW, p = e % HW;
            int pr = p / 32, pw_ = p % 32;
            u[c * 3 * PP + tsel * PP + (pr + 2) * PW + (pw_ + 2)] = src[e];
        }
    }
    __syncthreads();

    int wave = tid >> 6, lane = tid & 63;
    int o = og * 4 + wave;
    const float* wp = W1 + (size_t)o * 147;
    int pos = r * 64 + lane;
    if (pos < 225) {
        int oh = pos / 15, ow = pos % 15;
        const float* sl = u + (oh * 2) * PW + ow * 2;
        float aC = 0.f, aL = 0.f, aH = 0.f;
        #pragma unroll
        for (int c = 0; c < 3; ++c) {
            #pragma unroll
            for (int kh = 0; kh < 7; ++kh)
                #pragma unroll
                for (int kw = 0; kw < 7; ++kw) {
                    float w = wp[c * 49 + kh * 7 + kw];
                    tap16(w, sl[kh * PW + kw], sl[PP + kh * PW + kw],
                          sl[2 * PP + kh * PW + kw], aC, aL, aH);
                }
            sl += 3 * PP;
        }
        size_t N = (size_t)16 * 96 * 225;
        size_t oi = ((size_t)b * 96 + o) * 225 + pos;
        A[oi] = aC; A[N + oi] = aL; A[2 * N + oi] = aH;
    }
}

// conv2: block=(chunk,b,oh), thread=o. Staging fuses pool1(3x3 s2)+rt8 from
// conv1 raw sums A. slab: [cp][tsel(3)][r(5)][col(12)][par(2)]
template<int CC>
__launch_bounds__(256)
__global__ void conv2_kernel(const float* __restrict__ A, const float* __restrict__ WT,
                             float* __restrict__ P)
{
    constexpr int B = 16, Cin = 96, O = 256;
    constexpr int CP = CC / 2;
    constexpr size_t N = (size_t)B * O * 49;
    constexpr size_t NA = (size_t)B * 96 * 225;
    __shared__ __align__(16) float slab[CP * 360];
    int x = blockIdx.x;
    int oh   = x % 7;
    int b    = (x / 7) % B;
    int chunk = x / (7 * B);
    int c0 = chunk * CC;
    int tid = threadIdx.x;

    for (int i = tid; i < CP * 360; i += 256) {
        int cp = i / 360; int rem = i - cp * 360;
        int tsel = rem / 120; int rr = rem - tsel * 120;
        int r = rr / 24; int cpar = rr - r * 24;
        int col = cpar >> 1, par = cpar & 1;
        int c = c0 + cp * 2 + par;
        int ih = oh + r - 2, iw = col - 2;
        float v = 0.f;
        if (col < 11 && (unsigned)ih < 7u && (unsigned)iw < 7u) {
            const float* ap = A + (size_t)tsel * NA + ((size_t)b * 96 + c) * 225
                            + (ih * 2) * 15 + iw * 2;
            float m = 0.f;  // sums >= 0
            #pragma unroll
            for (int pi = 0; pi < 3; ++pi)
                #pragma unroll
                for (int pj = 0; pj < 3; ++pj)
                    m = fmaxf(m, ap[pi * 15 + pj]);
            v = rt8(m);
        }
        slab[i] = v;
    }
    __syncthreads();

    int o = tid;
    vf2 aC2[7], aL2[7], aH2[7];
    vf2 zero = {0.f, 0.f};
    #pragma unroll
    for (int u = 0; u < 7; ++u) { aC2[u] = zero; aL2[u] = zero; aH2[u] = zero; }

    for (int cp = 0; cp < CP; ++cp) {
        const float* wp = WT + (size_t)((c0 / 2 + cp) * 25) * (2 * O) + 2 * o;
        const float* sb = slab + cp * 360;
        #pragma unroll
        for (int r = 0; r < 5; ++r) {
            vf2 wr[5];
            #pragma unroll
            for (int kw = 0; kw < 5; ++kw)
                wr[kw] = *(const vf2*)(wp + (size_t)(r * 5 + kw) * (2 * O));
            vf2 X[12], L[12], U[12];
            #pragma unroll
            for (int i2 = 0; i2 < 12; ++i2) {
                X[i2] = *(const vf2*)(sb + r * 24 + i2 * 2);
                L[i2] = *(const vf2*)(sb + 120 + r * 24 + i2 * 2);
                U[i2] = *(const vf2*)(sb + 240 + r * 24 + i2 * 2);
            }
            #pragma unroll
            for (int ow = 0; ow < 7; ++ow)
                #pragma unroll
                for (int kw = 0; kw < 5; ++kw)
                    tap16v2(wr[kw], X[ow + kw], L[ow + kw], U[ow + kw],
                            aC2[ow], aL2[ow], aH2[ow]);
        }
    }

    float* Pc = P + (size_t)chunk * 3 * N;
    size_t rowbase = ((size_t)(b * 7 + oh) * 7) * O + o;
    #pragma unroll
    for (int u = 0; u < 7; ++u) {
        Pc[rowbase + (size_t)u * O]         = aC2[u].x + aC2[u].y;
        Pc[N + rowbase + (size_t)u * O]     = aL2[u].x + aL2[u].y;
        Pc[2 * N + rowbase + (size_t)u * O] = aH2[u].x + aH2[u].y;
    }
}

// Fused conv2-combine + pool2 + rt8. Output D pos-major: [tsel][b][pos(9)][256].
__global__ void comb2_pool2(const float* __restrict__ P, float* __restrict__ D)
{
    constexpr int B = 16, O = 256, NCH = 16;
    constexpr size_t N = (size_t)B * O * 49;
    int idx = blockIdx.x * blockDim.x + threadIdx.x;
    if (idx >= 3 * B * 9 * O) return;
    int o = idx & 255; int t = idx >> 8;
    int pos = t % 9; t /= 9;
    int b = t % B; int tsel = t / B;
    int ph = pos / 3, pw = pos % 3;
    float m = 0.f;
    #pragma unroll
    for (int i = 0; i < 3; ++i)
        #pragma unroll
        for (int j = 0; j < 3; ++j) {
            int sp = (ph * 2 + i) * 7 + (pw * 2 + j);
            size_t base = (size_t)tsel * N + ((size_t)b * 49 + sp) * O + o;
            float s = 0.f;
            #pragma unroll
            for (int ch = 0; ch < NCH; ++ch) s += P[(size_t)ch * 3 * N + base];
            m = fmaxf(m, s);
        }
    D[idx] = rt8(m);
}

// conv3/4/5: block=(chunk,b), thread=o, channel-pair packed.
// NCHIN==0: input IN is final pos-major [tsel][b][pos][Cin].
// NCHIN>0:  input IN is partial sums (NCHIN chunks); staging does rt8(sum).
template<int CC, int NCHIN>
__launch_bounds__(384)
__global__ void conv3x3_kernel(const float* __restrict__ IN, const float* __restrict__ WT,
                               float* __restrict__ P, int B, int Cin, int O)
{
    constexpr int CP = CC / 2;
    __shared__ __align__(8) float slab[CP * 150];
    int x = blockIdx.x;
    int b = x % B;
    int chunk = x / B;
    int c0 = chunk * CC;
    int tid = threadIdx.x;

    size_t NN = (size_t)B * Cin * 9;
    for (int i = tid; i < CP * 150; i += blockDim.x) {
        int cp = i / 150; int rem = i - cp * 150;
        int tsel = rem / 50; int rr = rem - tsel * 50;
        int p = rr >> 1, par = rr & 1;
        int iy = p / 5, ix = p - iy * 5;
        int ih = iy - 1, iw = ix - 1;
        int c = c0 + cp * 2 + par;
        float v = 0.f;
        if ((unsigned)ih < 3u && (unsigned)iw < 3u) {
            size_t base = (size_t)tsel * NN + ((size_t)b * 9 + (ih * 3 + iw)) * Cin + c;
            if (NCHIN == 0) {
                v = IN[base];
            } else {
                float s = 0.f;
                #pragma unroll 8
                for (int ch = 0; ch < NCHIN; ++ch) s += IN[(size_t)ch * 3 * NN + base];
                v = rt8(s);
            }
        }
        slab[i] = v;
    }
    __syncthreads();

    int o = tid;
    vf2 aC2[9], aL2[9], aH2[9];
    vf2 zero = {0.f, 0.f};
    #pragma unroll
    for (int u = 0; u < 9; ++u) { aC2[u] = zero; aL2[u] = zero; aH2[u] = zero; }

    for (int cp = 0; cp < CP; ++cp) {
        const float* wp = WT + (size_t)((c0 / 2 + cp) * 9) * (2 * O) + 2 * o;
        vf2 w2[9];
        #pragma unroll
        for (int t = 0; t < 9; ++t) w2[t] = *(const vf2*)(wp + (size_t)t * (2 * O));
        const float* sb = slab + cp * 150;
        #pragma unroll
        for (int py = 0; py < 3; ++py)
            #pragma unroll
            for (int px = 0; px < 3; ++px)
                #pragma unroll
                for (int ky = 0; ky < 3; ++ky)
                    #pragma unroll
                    for (int kx = 0; kx < 3; ++kx) {
                        int p = (py + ky) * 5 + (px + kx);
                        tap16v2(w2[ky * 3 + kx],
                                *(const vf2*)(sb + p * 2),
                                *(const vf2*)(sb + 50 + p * 2),
                                *(const vf2*)(sb + 100 + p * 2),
                                aC2[py * 3 + px], aL2[py * 3 + px], aH2[py * 3 + px]);
                    }
    }

    size_t N = (size_t)B * O * 9;
    float* Pc = P + (size_t)chunk * 3 * N;
    size_t base = ((size_t)b * 9) * O + o;
    #pragma unroll
    for (int u = 0; u < 9; ++u) {
        Pc[base + (size_t)u * O]         = aC2[u].x + aC2[u].y;
        Pc[N + base + (size_t)u * O]     = aL2[u].x + aL2[u].y;
        Pc[2 * N + base + (size_t)u * O] = aH2[u].x + aH2[u].y;
    }
}

// conv5 combine -> standard [tsel][b][O][9] layout for fc1.
__global__ void comb5_std(const float* __restrict__ P, float* __restrict__ G, int NCH)
{
    constexpr int B = 16, O = 256;
    constexpr size_t N = (size_t)B * O * 9;
    size_t idx = (size_t)blockIdx.x * blockDim.x + threadIdx.x;
    if (idx >= 3 * N) return;
    float s = 0.f;
    for (int ch = 0; ch < NCH; ++ch) s += P[(size_t)ch * 3 * N + idx];
    int o = (int)(idx % O); size_t t = idx / O;
    int pos = (int)(t % 9); t /= 9;
    int b = (int)(t % B); int tsel = (int)(t / B);
    G[(size_t)tsel * N + ((size_t)b * O + o) * 9 + pos] = rt8(s);
}

// fc1/fc2: wave per (o, b-group of 4); weight row read once per 4 batches.
__launch_bounds__(256)
__global__ void fc_gemv4(const float* __restrict__ IC, const float* __restrict__ IL,
                         const float* __restrict__ IU, const float* __restrict__ W,
                         float* __restrict__ OUT, int In, int Out)
{
    constexpr int B = 16;
    int gw = (int)((blockIdx.x * blockDim.x + threadIdx.x) >> 6);
    int lane = threadIdx.x & 63;
    if (gw >= Out * 4) return;
    int o = gw % Out, bg = gw / Out;
    int b0 = bg * 4;
    const float4* wr = (const float4*)(W + (size_t)o * In);
    const float4* cr[4]; const float4* lr[4]; const float4* ur[4];
    #pragma unroll
    for (int q = 0; q < 4; ++q) {
        cr[q] = (const float4*)(IC + (size_t)(b0 + q) * In);
        lr[q] = (const float4*)(IL + (size_t)(b0 + q) * In);
        ur[q] = (const float4*)(IU + (size_t)(b0 + q) * In);
    }
    int In4 = In >> 2;
    float sc[4] = {0.f, 0.f, 0.f, 0.f};
    float sm[4] = {0.f, 0.f, 0.f, 0.f};
    float sr[4] = {0.f, 0.f, 0.f, 0.f};
    for (int i = lane; i < In4; i += 64) {
        float4 w4 = wr[i];
        float ax = fabsf(w4.x), ay = fabsf(w4.y), az = fabsf(w4.z), aw = fabsf(w4.w);
        #pragma unroll
        for (int q = 0; q < 4; ++q) {
            float4 c4 = cr[q][i], l4 = lr[q][i], u4 = ur[q][i];
            sc[q] = fmaf(c4.x, w4.x, sc[q]); sc[q] = fmaf(c4.y, w4.y, sc[q]);
            sc[q] = fmaf(c4.z, w4.z, sc[q]); sc[q] = fmaf(c4.w, w4.w, sc[q]);
            sm[q] = fmaf((l4.x + u4.x) * 0.5f, w4.x, sm[q]);
            sm[q] = fmaf((l4.y + u4.y) * 0.5f, w4.y, sm[q]);
            sm[q] = fmaf((l4.z + u4.z) * 0.5f, w4.z, sm[q]);
            sm[q] = fmaf((l4.w + u4.w) * 0.5f, w4.w, sm[q]);
            sr[q] = fmaf((u4.x - l4.x) * 0.5f, ax, sr[q]);
            sr[q] = fmaf((u4.y - l4.y) * 0.5f, ay, sr[q]);
            sr[q] = fmaf((u4.z - l4.z) * 0.5f, az, sr[q]);
            sr[q] = fmaf((u4.w - l4.w) * 0.5f, aw, sr[q]);
        }
    }
    #pragma unroll
    for (int off = 32; off; off >>= 1) {
        #pragma unroll
        for (int q = 0; q < 4; ++q) {
            sc[q] += __shfl_xor(sc[q], off);
            sm[q] += __shfl_xor(sm[q], off);
            sr[q] += __shfl_xor(sr[q], off);
        }
    }
    if (lane == 0) {
        size_t N = (size_t)B * Out;
        #pragma unroll
        for (int q = 0; q < 4; ++q) {
            size_t idx = (size_t)(b0 + q) * Out + o;
            OUT[idx]         = fmaxf(sc[q], 0.f);
            OUT[N + idx]     = fmaxf(sm[q] - sr[q], 0.f);
            OUT[2 * N + idx] = fmaxf(sm[q] + sr[q], 0.f);
        }
    }
}

__global__ void bound_linear_kernel(
    const float* __restrict__ IC, const float* __restrict__ IL, const float* __restrict__ IU,
    const float* __restrict__ W, const float* __restrict__ bias,
    float* __restrict__ OC, float* __restrict__ OL, float* __restrict__ OU,
    int B, int In, int Out)
{
    int idx = blockIdx.x * blockDim.x + threadIdx.x;
    if (idx >= B * Out) return;
    int o = idx % Out, b = idx / Out;
    const float* wr = W  + (size_t)o * In;
    const float* cr = IC + (size_t)b * In;
    const float* lr = IL + (size_t)b * In;
    const float* ur = IU + (size_t)b * In;
    float sc = 0.f, sm = 0.f, sr = 0.f;
    for (int i = 0; i < In; ++i) {
        float w = wr[i];
        sc = fmaf(cr[i], w, sc);
        sm = fmaf((lr[i] + ur[i]) * 0.5f, w, sm);
        sr = fmaf((ur[i] - lr[i]) * 0.5f, fabsf(w), sr);
    }
    float bb = bias[o]; sc += bb; sm += bb;
    OC[idx] = -sc; OL[idx] = -(sm - sr); OU[idx] = -(sm + sr);
}

extern "C" void kernel_launch(void* const* d_in, const int* in_sizes, int n_in,
                              void* d_out, int out_size, void* d_ws, size_t ws_size,
                              hipStream_t stream)
{
    const float* x   = (const float*)d_in[0];
    const float* lo  = (const float*)d_in[1];
    const float* hi  = (const float*)d_in[2];
    const float* w1  = (const float*)d_in[3];
    const float* w2  = (const float*)d_in[4];
    const float* w3  = (const float*)d_in[5];
    const float* w4  = (const float*)d_in[6];
    const float* w5  = (const float*)d_in[7];
    const float* fw1 = (const float*)d_in[8];
    const float* fw2 = (const float*)d_in[9];
    const float* fw3 = (const float*)d_in[10];
    const float* fb3 = (const float*)d_in[11];
    float* out = (float*)d_out;
    float* ws  = (float*)d_ws;

    const size_t n_c1 = 16u * 96 * 225;       // conv1 raw
    const size_t n_d  = 16u * 256 * 9;        // pooled conv2, pos-major
    const size_t n_c5 = 16u * 256 * 9;
    const size_t n_f1 = 16u * 1024;
    const size_t n_f2 = 16u * 512;
    const size_t N3   = 16u * 384 * 9;        // conv3/conv4 plane

    float* A   = ws;                 // conv1 raw sums: 3*n_c1
    float* D   = A  + 3 * n_c1;      // pooled conv2, pos-major: 3*n_d
    float* G   = D  + 3 * n_d;       // conv5 combined, standard: 3*n_c5
    float* H   = G  + 3 * n_c5;      // fc1 out
    float* I   = H  + 3 * n_f1;      // fc2 out
    float* WT2 = I  + 3 * n_f2;      // 614400
    float* WT3 = WT2 + 614400;       // 884736
    float* WT4 = WT3 + 884736;       // 1327104
    float* WT5 = WT4 + 1327104;      // 884736
    float* SP2 = WT5 + 884736;       // conv2 partials: 16*3*200704 = 9.63M
    float* SPa = SP2;                // conv3 partials alias (SP2 dead): 32*3*N3
    float* SPc = SP2;                // conv5 partials alias (SPa dead)
    float* SPb = SP2 + 32u * 3 * N3; // conv4 partials: 48*3*N3

    const int BS = 256;
    auto grid = [](size_t tot) { return dim3((unsigned)((tot + 255) / 256)); };

    // prep: weight transposes (908 blocks) + conv1 (1536 blocks)
    prep_kernel<<<908 + 1536, BS, 0, stream>>>(
        w2, w3, w4, w5, WT2, WT3, WT4, WT5, x, lo, hi, w1, A);
    // conv2 (staging fuses pool1+rt8): NCH=16, CC=6; 1792 blocks
    conv2_kernel<6><<<16 * 16 * 7, 256, 0, stream>>>(A, WT2, SP2);
    // fused conv2-combine + pool2 + rt8 -> D pos-major
    comb2_pool2<<<grid(3 * n_d), BS, 0, stream>>>(SP2, D);
    // conv3: Cin=256 O=384; 32 chunks; direct staging from D
    conv3x3_kernel<8, 0><<<32 * 16, 384, 0, stream>>>(D, WT3, SPa, 16, 256, 384);
    // conv4: Cin=384 O=384; 48 chunks; staging = rt8(sum of 32 conv3 partials)
    conv3x3_kernel<8, 32><<<48 * 16, 384, 0, stream>>>(SPa, WT4, SPb, 16, 384, 384);
    // conv5: Cin=384 O=256; 48 chunks; staging = rt8(sum of 48 conv4 partials)
    conv3x3_kernel<8, 48><<<48 * 16, 256, 0, stream>>>(SPb, WT5, SPc, 16, 384, 256);
    // conv5 combine -> standard layout
    comb5_std<<<grid(3 * n_c5), BS, 0, stream>>>(SPc, G, 48);
    // fc1: 2304 -> 1024, relu; 4096 waves (4 b per wave)
    fc_gemv4<<<grid(4096u * 64), BS, 0, stream>>>(
        G, G + n_c5, G + 2 * n_c5, fw1, H, 2304, 1024);
    // fc2: 1024 -> 512, relu; 2048 waves
    fc_gemv4<<<grid(2048u * 64), BS, 0, stream>>>(
        H, H + n_f1, H + 2 * n_f1, fw2, I, 1024, 512);
    // fc3: 512 -> 10, +bias, negate+swap: out = [-c | -u | -l]
    bound_linear_kernel<<<grid(160), BS, 0, stream>>>(
        I, I + n_f2, I + 2 * n_f2, fw3, fb3,
        out, out + 320, out + 160, 16, 512, 10);
}

// Round 13
// 563.723 us; speedup vs baseline: 1.0700x; 1.0193x over previous
//
#include <hip/hip_runtime.h>
#include <math.h>

// ---------------------------------------------------------------------------
// NormDist (Lp, p=8) IBP AlexNet. Round 13 = Round 12 + conv3x3 LDS-pipe fix:
// iy-outer single-row register window (row = 18 vf2 = 36 VGPR live, not the
// r11 full-window 150) -> LDS insts/cp 243 -> 45 (9x ds_read_b128 per row).
// conv3x3 was LDS-issue-bound: 4 SIMDs share 1 LDS pipe; 243 b64 reads/cp
// ~ 1700W cyc vs 688W VALU share.
// Structure: prep(transpose+conv1) -> conv2(pool1 fused) -> comb2+pool2 ->
// conv3 -> conv4(comb3 fused) -> conv5(comb4 fused) -> comb5 -> fc1 -> fc2
// -> fc3. 10 launches. lp8(d)=(sum d^8)^(1/8); relu after conv = no-op.
// ---------------------------------------------------------------------------

typedef float vf2 __attribute__((ext_vector_type(2)));

__device__ __forceinline__ float rt8(float s) { return sqrtf(sqrtf(sqrtf(s))); }

__device__ __forceinline__ void tap16(float w, float pc, float pl, float pu,
                                      float& aC, float& aL, float& aH)
{
    float a = pc - w; float a2 = a * a, a4 = a2 * a2; aC = fmaf(a4, a4, aC);
    float x = pl - w, y = pu - w;
    float dl = fmaxf(fmaxf(x, -y), 0.f);
    float e2 = dl * dl, e4 = e2 * e2; aL = fmaf(e4, e4, aL);
    float h2 = fmaxf(x * x, y * y);
    float h4 = h2 * h2; aH = fmaf(h4, h4, aH);
}

__device__ __forceinline__ void tap16v2(vf2 w, vf2 pc, vf2 pl, vf2 pu,
                                        vf2& aC, vf2& aL, vf2& aH)
{
    vf2 a = pc - w; vf2 a2 = a * a, a4 = a2 * a2;
    aC = __builtin_elementwise_fma(a4, a4, aC);
    vf2 x = pl - w, y = pu - w;
    vf2 zero = {0.f, 0.f};
    vf2 dl = __builtin_elementwise_max(__builtin_elementwise_max(x, -y), zero);
    vf2 e2 = dl * dl, e4 = e2 * e2;
    aL = __builtin_elementwise_fma(e4, e4, aL);
    vf2 h2 = __builtin_elementwise_max(x * x, y * y);
    vf2 h4 = h2 * h2;
    aH = __builtin_elementwise_fma(h4, h4, aH);
}

// prep: bid < 908 -> 64x64 LDS-tiled transpose of w2..w5 into c-pair layout
// T[((c/2)*KK+t)*(2*O) + o*2 + (c&1)]; else conv1 (round-split, 1536 blocks).
__launch_bounds__(256)
__global__ void prep_kernel(const float* __restrict__ W2, const float* __restrict__ W3,
                            const float* __restrict__ W4, const float* __restrict__ W5,
                            float* __restrict__ T2, float* __restrict__ T3,
                            float* __restrict__ T4, float* __restrict__ T5,
                            const float* __restrict__ IC, const float* __restrict__ IL,
                            const float* __restrict__ IU, const float* __restrict__ W1,
                            float* __restrict__ A)
{
    constexpr int nt2 = 152, nt3 = 216, nt4 = 324, nt5 = 216;
    constexpr int NTW = nt2 + nt3 + nt4 + nt5;  // 908
    __shared__ float u[3 * 3 * 1225];           // conv1 35x35 slab; >= 64*65
    int bid = blockIdx.x;
    int tid = threadIdx.x;

    if (bid < NTW) {
        const float* W; float* T; int O, CK, KK, t;
        if (bid < nt2)                  { W = W2; T = T2; O = 256; CK = 2400; KK = 25; t = bid; }
        else if (bid < nt2 + nt3)       { W = W3; T = T3; O = 384; CK = 2304; KK = 9; t = bid - nt2; }
        else if (bid < nt2 + nt3 + nt4) { W = W4; T = T4; O = 384; CK = 3456; KK = 9; t = bid - nt2 - nt3; }
        else                            { W = W5; T = T5; O = 256; CK = 3456; KK = 9; t = bid - nt2 - nt3 - nt4; }
        int tilesC = (CK + 63) / 64;
        int to = t / tilesC, tc = t - to * tilesC;
        int o0 = to * 64, c0 = tc * 64;
        int lane = tid & 63, wv = tid >> 6;
        #pragma unroll
        for (int i = 0; i < 16; ++i) {
            int row = wv + i * 4;
            int c = c0 + lane;
            u[row * 65 + lane] = (c < CK) ? W[(size_t)(o0 + row) * CK + c] : 0.f;
        }
        __syncthreads();
        #pragma unroll
        for (int i = 0; i < 16; ++i) {
            int row = wv + i * 4;
            int ck = c0 + row;
            if (ck < CK) {
                int c = ck / KK, tt = ck - c * KK;
                T[(size_t)((c >> 1) * KK + tt) * (2 * O) + (size_t)(o0 + lane) * 2 + (c & 1)]
                    = u[lane * 65 + row];
            }
        }
        return;
    }

    // conv1: [16,3,32,32] k7 s2 p2 -> raw d^8 sums [3][16,96,15,15]
    constexpr int PP = 1225, PW = 35, HW = 1024;
    int t = bid - NTW;
    int og = t % 24; t /= 24;
    int b  = t % 16; int r = t / 16;   // r in [0,4)

    for (int i = tid; i < 3 * 3 * PP; i += 256) u[i] = 0.f;
    __syncthreads();
    for (int tsel = 0; tsel < 3; ++tsel) {
        const float* src = (tsel == 0 ? IC : (tsel == 1 ? IL : IU)) + (size_t)b * 3 * HW;
        for (int e = tid; e < 3 * HW; e += 256) {
            int c = e / HW, p = e % HW;
            int pr = p / 32, pw_ = p % 32;
            u[c * 3 * PP + tsel * PP + (pr + 2) * PW + (pw_ + 2)] = src[e];
        }
    }
    __syncthreads();

    int wave = tid >> 6, lane = tid & 63;
    int o = og * 4 + wave;
    const float* wp = W1 + (size_t)o * 147;
    int pos = r * 64 + lane;
    if (pos < 225) {
        int oh = pos / 15, ow = pos % 15;
        const float* sl = u + (oh * 2) * PW + ow * 2;
        float aC = 0.f, aL = 0.f, aH = 0.f;
        #pragma unroll
        for (int c = 0; c < 3; ++c) {
            #pragma unroll
            for (int kh = 0; kh < 7; ++kh)
                #pragma unroll
                for (int kw = 0; kw < 7; ++kw) {
                    float w = wp[c * 49 + kh * 7 + kw];
                    tap16(w, sl[kh * PW + kw], sl[PP + kh * PW + kw],
                          sl[2 * PP + kh * PW + kw], aC, aL, aH);
                }
            sl += 3 * PP;
        }
        size_t N = (size_t)16 * 96 * 225;
        size_t oi = ((size_t)b * 96 + o) * 225 + pos;
        A[oi] = aC; A[N + oi] = aL; A[2 * N + oi] = aH;
    }
}

// conv2: block=(chunk,b,oh), thread=o. Staging fuses pool1(3x3 s2)+rt8 from
// conv1 raw sums A. slab: [cp][tsel(3)][r(5)][col(12)][par(2)]
template<int CC>
__launch_bounds__(256)
__global__ void conv2_kernel(const float* __restrict__ A, const float* __restrict__ WT,
                             float* __restrict__ P)
{
    constexpr int B = 16, Cin = 96, O = 256;
    constexpr int CP = CC / 2;
    constexpr size_t N = (size_t)B * O * 49;
    constexpr size_t NA = (size_t)B * 96 * 225;
    __shared__ __align__(16) float slab[CP * 360];
    int x = blockIdx.x;
    int oh   = x % 7;
    int b    = (x / 7) % B;
    int chunk = x / (7 * B);
    int c0 = chunk * CC;
    int tid = threadIdx.x;

    for (int i = tid; i < CP * 360; i += 256) {
        int cp = i / 360; int rem = i - cp * 360;
        int tsel = rem / 120; int rr = rem - tsel * 120;
        int r = rr / 24; int cpar = rr - r * 24;
        int col = cpar >> 1, par = cpar & 1;
        int c = c0 + cp * 2 + par;
        int ih = oh + r - 2, iw = col - 2;
        float v = 0.f;
        if (col < 11 && (unsigned)ih < 7u && (unsigned)iw < 7u) {
            const float* ap = A + (size_t)tsel * NA + ((size_t)b * 96 + c) * 225
                            + (ih * 2) * 15 + iw * 2;
            float m = 0.f;  // sums >= 0
            #pragma unroll
            for (int pi = 0; pi < 3; ++pi)
                #pragma unroll
                for (int pj = 0; pj < 3; ++pj)
                    m = fmaxf(m, ap[pi * 15 + pj]);
            v = rt8(m);
        }
        slab[i] = v;
    }
    __syncthreads();

    int o = tid;
    vf2 aC2[7], aL2[7], aH2[7];
    vf2 zero = {0.f, 0.f};
    #pragma unroll
    for (int u = 0; u < 7; ++u) { aC2[u] = zero; aL2[u] = zero; aH2[u] = zero; }

    for (int cp = 0; cp < CP; ++cp) {
        const float* wp = WT + (size_t)((c0 / 2 + cp) * 25) * (2 * O) + 2 * o;
        const float* sb = slab + cp * 360;
        #pragma unroll
        for (int r = 0; r < 5; ++r) {
            vf2 wr[5];
            #pragma unroll
            for (int kw = 0; kw < 5; ++kw)
                wr[kw] = *(const vf2*)(wp + (size_t)(r * 5 + kw) * (2 * O));
            vf2 X[12], L[12], U[12];
            #pragma unroll
            for (int i2 = 0; i2 < 12; ++i2) {
                X[i2] = *(const vf2*)(sb + r * 24 + i2 * 2);
                L[i2] = *(const vf2*)(sb + 120 + r * 24 + i2 * 2);
                U[i2] = *(const vf2*)(sb + 240 + r * 24 + i2 * 2);
            }
            #pragma unroll
            for (int ow = 0; ow < 7; ++ow)
                #pragma unroll
                for (int kw = 0; kw < 5; ++kw)
                    tap16v2(wr[kw], X[ow + kw], L[ow + kw], U[ow + kw],
                            aC2[ow], aL2[ow], aH2[ow]);
        }
    }

    float* Pc = P + (size_t)chunk * 3 * N;
    size_t rowbase = ((size_t)(b * 7 + oh) * 7) * O + o;
    #pragma unroll
    for (int u = 0; u < 7; ++u) {
        Pc[rowbase + (size_t)u * O]         = aC2[u].x + aC2[u].y;
        Pc[N + rowbase + (size_t)u * O]     = aL2[u].x + aL2[u].y;
        Pc[2 * N + rowbase + (size_t)u * O] = aH2[u].x + aH2[u].y;
    }
}

// Fused conv2-combine + pool2 + rt8. Output D pos-major: [tsel][b][pos(9)][256].
__global__ void comb2_pool2(const float* __restrict__ P, float* __restrict__ D)
{
    constexpr int B = 16, O = 256, NCH = 16;
    constexpr size_t N = (size_t)B * O * 49;
    int idx = blockIdx.x * blockDim.x + threadIdx.x;
    if (idx >= 3 * B * 9 * O) return;
    int o = idx & 255; int t = idx >> 8;
    int pos = t % 9; t /= 9;
    int b = t % B; int tsel = t / B;
    int ph = pos / 3, pw = pos % 3;
    float m = 0.f;
    #pragma unroll
    for (int i = 0; i < 3; ++i)
        #pragma unroll
        for (int j = 0; j < 3; ++j) {
            int sp = (ph * 2 + i) * 7 + (pw * 2 + j);
            size_t base = (size_t)tsel * N + ((size_t)b * 49 + sp) * O + o;
            float s = 0.f;
            #pragma unroll
            for (int ch = 0; ch < NCH; ++ch) s += P[(size_t)ch * 3 * N + base];
            m = fmaxf(m, s);
        }
    D[idx] = rt8(m);
}

// conv3/4/5: block=(chunk,b), thread=o, channel-pair packed.
// slab: [cp][tsel(3)][iy(5)][col(6)][par(2)] -- rows padded to 12 floats so a
// row is 3x ds_read_b128; col 5 is zero pad. iy-outer single-row register
// window: 45 LDS insts/cp, ~36 VGPR row state.
// NCHIN==0: input IN is final pos-major [tsel][b][pos][Cin].
// NCHIN>0:  input IN is partial sums (NCHIN chunks); staging does rt8(sum).
template<int CC, int NCHIN>
__launch_bounds__(384)
__global__ void conv3x3_kernel(const float* __restrict__ IN, const float* __restrict__ WT,
                               float* __restrict__ P, int B, int Cin, int O)
{
    constexpr int CP = CC / 2;
    __shared__ __align__(16) float slab[CP * 180];
    int x = blockIdx.x;
    int b = x % B;
    int chunk = x / B;
    int c0 = chunk * CC;
    int tid = threadIdx.x;

    size_t NN = (size_t)B * Cin * 9;
    for (int i = tid; i < CP * 180; i += blockDim.x) {
        int cp = i / 180; int rem = i - cp * 180;
        int tsel = rem / 60; int rr = rem - tsel * 60;
        int iy = rr / 12; int cc2 = rr - iy * 12;
        int col = cc2 >> 1, par = cc2 & 1;
        int ih = iy - 1, iw = col - 1;
        int c = c0 + cp * 2 + par;
        float v = 0.f;
        if ((unsigned)ih < 3u && (unsigned)iw < 3u) {
            size_t base = (size_t)tsel * NN + ((size_t)b * 9 + (ih * 3 + iw)) * Cin + c;
            if (NCHIN == 0) {
                v = IN[base];
            } else {
                float s = 0.f;
                #pragma unroll 8
                for (int ch = 0; ch < NCHIN; ++ch) s += IN[(size_t)ch * 3 * NN + base];
                v = rt8(s);
            }
        }
        slab[i] = v;
    }
    __syncthreads();

    int o = tid;
    vf2 aC2[9], aL2[9], aH2[9];
    vf2 zero = {0.f, 0.f};
    #pragma unroll
    for (int u = 0; u < 9; ++u) { aC2[u] = zero; aL2[u] = zero; aH2[u] = zero; }

    for (int cp = 0; cp < CP; ++cp) {
        const float* wp = WT + (size_t)((c0 / 2 + cp) * 9) * (2 * O) + 2 * o;
        vf2 w2[9];
        #pragma unroll
        for (int t = 0; t < 9; ++t) w2[t] = *(const vf2*)(wp + (size_t)t * (2 * O));
        const float* sb = slab + cp * 180;
        #pragma unroll
        for (int iy = 0; iy < 5; ++iy) {
            // load one padded row (6 positions x 3 tensors) via 9x b128
            vf2 X[6], L[6], U[6];
            {
                float4 x0 = *(const float4*)(sb + iy * 12);
                float4 x1 = *(const float4*)(sb + iy * 12 + 4);
                float4 x2 = *(const float4*)(sb + iy * 12 + 8);
                X[0] = vf2{x0.x, x0.y}; X[1] = vf2{x0.z, x0.w};
                X[2] = vf2{x1.x, x1.y}; X[3] = vf2{x1.z, x1.w};
                X[4] = vf2{x2.x, x2.y}; X[5] = vf2{x2.z, x2.w};
                float4 l0 = *(const float4*)(sb + 60 + iy * 12);
                float4 l1 = *(const float4*)(sb + 60 + iy * 12 + 4);
                float4 l2 = *(const float4*)(sb + 60 + iy * 12 + 8);
                L[0] = vf2{l0.x, l0.y}; L[1] = vf2{l0.z, l0.w};
                L[2] = vf2{l1.x, l1.y}; L[3] = vf2{l1.z, l1.w};
                L[4] = vf2{l2.x, l2.y}; L[5] = vf2{l2.z, l2.w};
                float4 u0 = *(const float4*)(sb + 120 + iy * 12);
                float4 u1 = *(const float4*)(sb + 120 + iy * 12 + 4);
                float4 u2 = *(const float4*)(sb + 120 + iy * 12 + 8);
                U[0] = vf2{u0.x, u0.y}; U[1] = vf2{u0.z, u0.w};
                U[2] = vf2{u1.x, u1.y}; U[3] = vf2{u1.z, u1.w};
                U[4] = vf2{u2.x, u2.y}; U[5] = vf2{u2.z, u2.w};
            }
            #pragma unroll
            for (int ky = 0; ky < 3; ++ky) {
                int py = iy - ky;
                if (py < 0 || py > 2) continue;   // folds at compile time
                #pragma unroll
                for (int px = 0; px < 3; ++px)
                    #pragma unroll
                    for (int kx = 0; kx < 3; ++kx)
                        tap16v2(w2[ky * 3 + kx], X[px + kx], L[px + kx], U[px + kx],
                                aC2[py * 3 + px], aL2[py * 3 + px], aH2[py * 3 + px]);
            }
        }
    }

    size_t N = (size_t)B * O * 9;
    float* Pc = P + (size_t)chunk * 3 * N;
    size_t base = ((size_t)b * 9) * O + o;
    #pragma unroll
    for (int u = 0; u < 9; ++u) {
        Pc[base + (size_t)u * O]         = aC2[u].x + aC2[u].y;
        Pc[N + base + (size_t)u * O]     = aL2[u].x + aL2[u].y;
        Pc[2 * N + base + (size_t)u * O] = aH2[u].x + aH2[u].y;
    }
}

// conv5 combine -> standard [tsel][b][O][9] layout for fc1.
__global__ void comb5_std(const float* __restrict__ P, float* __restrict__ G, int NCH)
{
    constexpr int B = 16, O = 256;
    constexpr size_t N = (size_t)B * O * 9;
    size_t idx = (size_t)blockIdx.x * blockDim.x + threadIdx.x;
    if (idx >= 3 * N) return;
    float s = 0.f;
    for (int ch = 0; ch < NCH; ++ch) s += P[(size_t)ch * 3 * N + idx];
    int o = (int)(idx % O); size_t t = idx / O;
    int pos = (int)(t % 9); t /= 9;
    int b = (int)(t % B); int tsel = (int)(t / B);
    G[(size_t)tsel * N + ((size_t)b * O + o) * 9 + pos] = rt8(s);
}

// fc1/fc2: wave per (o, b-group of 4); weight row read once per 4 batches.
__launch_bounds__(256)
__global__ void fc_gemv4(const float* __restrict__ IC, const float* __restrict__ IL,
                         const float* __restrict__ IU, const float* __restrict__ W,
                         float* __restrict__ OUT, int In, int Out)
{
    constexpr int B = 16;
    int gw = (int)((blockIdx.x * blockDim.x + threadIdx.x) >> 6);
    int lane = threadIdx.x & 63;
    if (gw >= Out * 4) return;
    int o = gw % Out, bg = gw / Out;
    int b0 = bg * 4;
    const float4* wr = (const float4*)(W + (size_t)o * In);
    const float4* cr[4]; const float4* lr[4]; const float4* ur[4];
    #pragma unroll
    for (int q = 0; q < 4; ++q) {
        cr[q] = (const float4*)(IC + (size_t)(b0 + q) * In);
        lr[q] = (const float4*)(IL + (size_t)(b0 + q) * In);
        ur[q] = (const float4*)(IU + (size_t)(b0 + q) * In);
    }
    int In4 = In >> 2;
    float sc[4] = {0.f, 0.f, 0.f, 0.f};
    float sm[4] = {0.f, 0.f, 0.f, 0.f};
    float sr[4] = {0.f, 0.f, 0.f, 0.f};
    for (int i = lane; i < In4; i += 64) {
        float4 w4 = wr[i];
        float ax = fabsf(w4.x), ay = fabsf(w4.y), az = fabsf(w4.z), aw = fabsf(w4.w);
        #pragma unroll
        for (int q = 0; q < 4; ++q) {
            float4 c4 = cr[q][i], l4 = lr[q][i], u4 = ur[q][i];
            sc[q] = fmaf(c4.x, w4.x, sc[q]); sc[q] = fmaf(c4.y, w4.y, sc[q]);
            sc[q] = fmaf(c4.z, w4.z, sc[q]); sc[q] = fmaf(c4.w, w4.w, sc[q]);
            sm[q] = fmaf((l4.x + u4.x) * 0.5f, w4.x, sm[q]);
            sm[q] = fmaf((l4.y + u4.y) * 0.5f, w4.y, sm[q]);
            sm[q] = fmaf((l4.z + u4.z) * 0.5f, w4.z, sm[q]);
            sm[q] = fmaf((l4.w + u4.w) * 0.5f, w4.w, sm[q]);
            sr[q] = fmaf((u4.x - l4.x) * 0.5f, ax, sr[q]);
            sr[q] = fmaf((u4.y - l4.y) * 0.5f, ay, sr[q]);
            sr[q] = fmaf((u4.z - l4.z) * 0.5f, az, sr[q]);
            sr[q] = fmaf((u4.w - l4.w) * 0.5f, aw, sr[q]);
        }
    }
    #pragma unroll
    for (int off = 32; off; off >>= 1) {
        #pragma unroll
        for (int q = 0; q < 4; ++q) {
            sc[q] += __shfl_xor(sc[q], off);
            sm[q] += __shfl_xor(sm[q], off);
            sr[q] += __shfl_xor(sr[q], off);
        }
    }
    if (lane == 0) {
        size_t N = (size_t)B * Out;
        #pragma unroll
        for (int q = 0; q < 4; ++q) {
            size_t idx = (size_t)(b0 + q) * Out + o;
            OUT[idx]         = fmaxf(sc[q], 0.f);
            OUT[N + idx]     = fmaxf(sm[q] - sr[q], 0.f);
            OUT[2 * N + idx] = fmaxf(sm[q] + sr[q], 0.f);
        }
    }
}

__global__ void bound_linear_kernel(
    const float* __restrict__ IC, const float* __restrict__ IL, const float* __restrict__ IU,
    const float* __restrict__ W, const float* __restrict__ bias,
    float* __restrict__ OC, float* __restrict__ OL, float* __restrict__ OU,
    int B, int In, int Out)
{
    int idx = blockIdx.x * blockDim.x + threadIdx.x;
    if (idx >= B * Out) return;
    int o = idx % Out, b = idx / Out;
    const float* wr = W  + (size_t)o * In;
    const float* cr = IC + (size_t)b * In;
    const float* lr = IL + (size_t)b * In;
    const float* ur = IU + (size_t)b * In;
    float sc = 0.f, sm = 0.f, sr = 0.f;
    for (int i = 0; i < In; ++i) {
        float w = wr[i];
        sc = fmaf(cr[i], w, sc);
        sm = fmaf((lr[i] + ur[i]) * 0.5f, w, sm);
        sr = fmaf((ur[i] - lr[i]) * 0.5f, fabsf(w), sr);
    }
    float bb = bias[o]; sc += bb; sm += bb;
    OC[idx] = -sc; OL[idx] = -(sm - sr); OU[idx] = -(sm + sr);
}

extern "C" void kernel_launch(void* const* d_in, const int* in_sizes, int n_in,
                              void* d_out, int out_size, void* d_ws, size_t ws_size,
                              hipStream_t stream)
{
    const float* x   = (const float*)d_in[0];
    const float* lo  = (const float*)d_in[1];
    const float* hi  = (const float*)d_in[2];
    const float* w1  = (const float*)d_in[3];
    const float* w2  = (const float*)d_in[4];
    const float* w3  = (const float*)d_in[5];
    const float* w4  = (const float*)d_in[6];
    const float* w5  = (const float*)d_in[7];
    const float* fw1 = (const float*)d_in[8];
    const float* fw2 = (const float*)d_in[9];
    const float* fw3 = (const float*)d_in[10];
    const float* fb3 = (const float*)d_in[11];
    float* out = (float*)d_out;
    float* ws  = (float*)d_ws;

    const size_t n_c1 = 16u * 96 * 225;       // conv1 raw
    const size_t n_d  = 16u * 256 * 9;        // pooled conv2, pos-major
    const size_t n_c5 = 16u * 256 * 9;
    const size_t n_f1 = 16u * 1024;
    const size_t n_f2 = 16u * 512;
    const size_t N3   = 16u * 384 * 9;        // conv3/conv4 plane

    float* A   = ws;                 // conv1 raw sums: 3*n_c1
    float* D   = A  + 3 * n_c1;      // pooled conv2, pos-major: 3*n_d
    float* G   = D  + 3 * n_d;       // conv5 combined, standard: 3*n_c5
    float* H   = G  + 3 * n_c5;      // fc1 out
    float* I   = H  + 3 * n_f1;      // fc2 out
    float* WT2 = I  + 3 * n_f2;      // 614400
    float* WT3 = WT2 + 614400;       // 884736
    float* WT4 = WT3 + 884736;       // 1327104
    float* WT5 = WT4 + 1327104;      // 884736
    float* SP2 = WT5 + 884736;       // conv2 partials: 16*3*200704 = 9.63M
    float* SPa = SP2;                // conv3 partials alias (SP2 dead): 32*3*N3
    float* SPc = SP2;                // conv5 partials alias (SPa dead)
    float* SPb = SP2 + 32u * 3 * N3; // conv4 partials: 48*3*N3

    const int BS = 256;
    auto grid = [](size_t tot) { return dim3((unsigned)((tot + 255) / 256)); };

    // prep: weight transposes (908 blocks) + conv1 (1536 blocks)
    prep_kernel<<<908 + 1536, BS, 0, stream>>>(
        w2, w3, w4, w5, WT2, WT3, WT4, WT5, x, lo, hi, w1, A);
    // conv2 (staging fuses pool1+rt8): NCH=16, CC=6; 1792 blocks
    conv2_kernel<6><<<16 * 16 * 7, 256, 0, stream>>>(A, WT2, SP2);
    // fused conv2-combine + pool2 + rt8 -> D pos-major
    comb2_pool2<<<grid(3 * n_d), BS, 0, stream>>>(SP2, D);
    // conv3: Cin=256 O=384; 32 chunks; direct staging from D
    conv3x3_kernel<8, 0><<<32 * 16, 384, 0, stream>>>(D, WT3, SPa, 16, 256, 384);
    // conv4: Cin=384 O=384; 48 chunks; staging = rt8(sum of 32 conv3 partials)
    conv3x3_kernel<8, 32><<<48 * 16, 384, 0, stream>>>(SPa, WT4, SPb, 16, 384, 384);
    // conv5: Cin=384 O=256; 48 chunks; staging = rt8(sum of 48 conv4 partials)
    conv3x3_kernel<8, 48><<<48 * 16, 256, 0, stream>>>(SPb, WT5, SPc, 16, 384, 256);
    // conv5 combine -> standard layout
    comb5_std<<<grid(3 * n_c5), BS, 0, stream>>>(SPc, G, 48);
    // fc1: 2304 -> 1024, relu; 4096 waves (4 b per wave)
    fc_gemv4<<<grid(4096u * 64), BS, 0, stream>>>(
        G, G + n_c5, G + 2 * n_c5, fw1, H, 2304, 1024);
    // fc2: 1024 -> 512, relu; 2048 waves
    fc_gemv4<<<grid(2048u * 64), BS, 0, stream>>>(
        H, H + n_f1, H + 2 * n_f1, fw2, I, 1024, 512);
    // fc3: 512 -> 10, +bias, negate+swap: out = [-c | -u | -l]
    bound_linear_kernel<<<grid(160), BS, 0, stream>>>(
        I, I + n_f2, I + 2 * n_f2, fw3, fb3,
        out, out + 320, out + 160, 16, 512, 10);
}